// Round 1
// 674.252 us; speedup vs baseline: 1.0091x; 1.0091x over previous
//
#include <hip/hip_runtime.h>
#include <math.h>

#define NODES 10000
#define NEDGE 320000
#define INDIM 512
#define CH    128
#define GB1   157   // fused-gemm row-tile blocks (64 rows each)
#define FB    313   // ELL fill blocks (mixed into kA)
#define ZB    2500  // z2 blocks (4 waves each -> 10000 rows)
#define AB    2500  // agg blocks (4 waves each -> 10000 nodes)
#define SB    2500  // score blocks
#define MAXDEG 96   // ELL row capacity (in-degree lambda=32; P(>96) ~ 1e-19)

typedef float f32x4 __attribute__((ext_vector_type(4)));
typedef short s16x8 __attribute__((ext_vector_type(8)));
typedef short s16x4 __attribute__((ext_vector_type(4)));

__device__ __forceinline__ short f2bf(float f) {
    unsigned u = __float_as_uint(f);
    return (short)((u + 0x7fffu + ((u >> 16) & 1u)) >> 16);
}
__device__ __forceinline__ float bf2f(short s) {
    return __uint_as_float(((unsigned)(unsigned short)s) << 16);
}
__device__ __forceinline__ float sigmoidf(float v) {
    return 1.f / (1.f + __expf(-v));
}

// LDS layout (bytes). Stage1 uses Ah/Al + Bh/Bl. Stage2 reuses [0,33792) for the
// bf16-split h tile (Ah2/Al2) -- legal because all stage-1 MFMAs are barrier-drained
// before the overwrite -- and restages Bh/Bl in place from Wg.
#define SROW   72    // stage-1 LDS row pitch (shorts): 64 k + 8 pad
#define SROW2  132   // stage-2 A row pitch (shorts): 128 k + 4 pad (odd dword stride)
#define AH_OFF  0        // 64*72*2  = 9216
#define AL_OFF  9216     // 9216
#define BH_OFF  33792    // 128*72*2 = 18432
#define BL_OFF  52224    // 18432  (end 70656)
#define AH2_OFF 0        // 64*132*2 = 16896
#define AL2_OFF 16896    // 16896  (end 33792 == BH_OFF)
#define SMEM_SZ 70656

// ---- kA: per 64-row tile, fused  h = l2n(x@W2^T + b2)*1.8  ->  xw = h@Wg^T ----
//      h never leaves LDS. Blocks >= GB1 do the ELL fill (cursor pre-zeroed by memset).
__global__ __launch_bounds__(256) void kA(const float* __restrict__ x,
                                          const float* __restrict__ W2,
                                          const float* __restrict__ b2,
                                          const float* __restrict__ Wg,
                                          const int* __restrict__ ei,
                                          int* cursor, int2* __restrict__ ell,
                                          float* __restrict__ xw) {
    __shared__ __align__(16) char smem[SMEM_SZ];
    int b = blockIdx.x;
    int tid = threadIdx.x;
    if (b >= GB1) {
        // ---- ELL fill: independent of the GEMMs, overlaps with them here ----
        for (int e = (b - GB1) * 256 + tid; e < NEDGE; e += FB * 256) {
            int c = ei[NEDGE + e], src = ei[e];
            int pos = atomicAdd(&cursor[c], 1);
            if (pos < MAXDEG) ell[c * MAXDEG + pos] = make_int2(src, e);
        }
        return;
    }
    short* Ah  = (short*)(smem + AH_OFF);
    short* Al  = (short*)(smem + AL_OFF);
    short* Bh  = (short*)(smem + BH_OFF);
    short* Bl  = (short*)(smem + BL_OFF);
    short* Ah2 = (short*)(smem + AH2_OFF);
    short* Al2 = (short*)(smem + AL2_OFF);

    int wave = tid >> 6, lane = tid & 63, quad = lane >> 4, l16 = lane & 15;
    int row0 = b * 64;

    // ================= stage 1: acc = x_tile @ W2^T =================
    f32x4 acc[8];
#pragma unroll
    for (int t = 0; t < 8; t++) acc[t] = (f32x4){0.f, 0.f, 0.f, 0.f};

    for (int kb = 0; kb < INDIM; kb += 64) {
        __syncthreads();
#pragma unroll
        for (int i = 0; i < 4; i++) {  // A tile: 64 rows x 64 k (split bf16 hi/lo)
            int idx = tid + 256 * i;
            int j = idx & 15, r = idx >> 4;
            float4 v = {0.f, 0.f, 0.f, 0.f};
            int grow = row0 + r;
            if (grow < NODES) v = *(const float4*)(x + (size_t)grow * INDIM + kb + 4 * j);
            float vv[4] = {v.x, v.y, v.z, v.w};
            s16x4 h4, l4;
#pragma unroll
            for (int q = 0; q < 4; q++) {
                short hs = f2bf(vv[q]);
                h4[q] = hs;
                l4[q] = f2bf(vv[q] - bf2f(hs));
            }
            *(s16x4*)&Ah[r * SROW + 4 * j] = h4;
            *(s16x4*)&Al[r * SROW + 4 * j] = l4;
        }
#pragma unroll
        for (int i = 0; i < 8; i++) {  // B tile: 128 n x 64 k from W2
            int idx = tid + 256 * i;
            int j = idx & 15, n = idx >> 4;
            float4 v = *(const float4*)(W2 + (size_t)n * INDIM + kb + 4 * j);
            float vv[4] = {v.x, v.y, v.z, v.w};
            s16x4 h4, l4;
#pragma unroll
            for (int q = 0; q < 4; q++) {
                short hs = f2bf(vv[q]);
                h4[q] = hs;
                l4[q] = f2bf(vv[q] - bf2f(hs));
            }
            *(s16x4*)&Bh[n * SROW + 4 * j] = h4;
            *(s16x4*)&Bl[n * SROW + 4 * j] = l4;
        }
        __syncthreads();

#pragma unroll
        for (int kk = 0; kk < 64; kk += 32) {
            int aoff = (wave * 16 + l16) * SROW + kk + quad * 8;
            s16x8 ah = *(const s16x8*)&Ah[aoff];
            s16x8 al = *(const s16x8*)&Al[aoff];
#pragma unroll
            for (int t = 0; t < 8; t++) {
                int boff = (t * 16 + l16) * SROW + kk + quad * 8;
                s16x8 bh = *(const s16x8*)&Bh[boff];
                s16x8 bl = *(const s16x8*)&Bl[boff];
                acc[t] = __builtin_amdgcn_mfma_f32_16x16x32_bf16(ah, bh, acc[t], 0, 0, 0);
                acc[t] = __builtin_amdgcn_mfma_f32_16x16x32_bf16(ah, bl, acc[t], 0, 0, 0);
                acc[t] = __builtin_amdgcn_mfma_f32_16x16x32_bf16(al, bh, acc[t], 0, 0, 0);
            }
        }
    }

    // bias + row l2-normalize * 1.8  (row cols live across the 16 lanes of each quad)
#pragma unroll
    for (int t = 0; t < 8; t++) {
        float bv = b2[t * 16 + l16];
#pragma unroll
        for (int r = 0; r < 4; r++) acc[t][r] += bv;
    }
#pragma unroll
    for (int r = 0; r < 4; r++) {
        float ss = 0.f;
#pragma unroll
        for (int t = 0; t < 8; t++) ss += acc[t][r] * acc[t][r];
#pragma unroll
        for (int off = 1; off < 16; off <<= 1) ss += __shfl_xor(ss, off, 64);
        float scale = 1.8f / fmaxf(sqrtf(ss), 1e-12f);
#pragma unroll
        for (int t = 0; t < 8; t++) acc[t][r] *= scale;
    }

    // ================= h tile -> LDS (bf16 hi/lo), becomes stage-2 A =================
    __syncthreads();  // drain all stage-1 LDS reads before overwriting [0,33792)
#pragma unroll
    for (int t = 0; t < 8; t++) {
#pragma unroll
        for (int r = 0; r < 4; r++) {
            int row = wave * 16 + quad * 4 + r;
            int col = t * 16 + l16;
            float v = acc[t][r];
            short hs = f2bf(v);
            Ah2[row * SROW2 + col] = hs;
            Al2[row * SROW2 + col] = f2bf(v - bf2f(hs));
        }
    }

    // ================= stage 2: acc2 = h_tile @ Wg^T (K=128) =================
    f32x4 acc2[8];
#pragma unroll
    for (int t = 0; t < 8; t++) acc2[t] = (f32x4){0.f, 0.f, 0.f, 0.f};

    for (int kb = 0; kb < CH; kb += 64) {
        __syncthreads();  // also orders Ah2/Al2 writes before first MFMA read
#pragma unroll
        for (int i = 0; i < 8; i++) {  // B tile: 128 n x 64 k from Wg
            int idx = tid + 256 * i;
            int j = idx & 15, n = idx >> 4;
            float4 v = *(const float4*)(Wg + (size_t)n * CH + kb + 4 * j);
            float vv[4] = {v.x, v.y, v.z, v.w};
            s16x4 h4, l4;
#pragma unroll
            for (int q = 0; q < 4; q++) {
                short hs = f2bf(vv[q]);
                h4[q] = hs;
                l4[q] = f2bf(vv[q] - bf2f(hs));
            }
            *(s16x4*)&Bh[n * SROW + 4 * j] = h4;
            *(s16x4*)&Bl[n * SROW + 4 * j] = l4;
        }
        __syncthreads();

#pragma unroll
        for (int kk = 0; kk < 64; kk += 32) {
            int aoff = (wave * 16 + l16) * SROW2 + kb + kk + quad * 8;
            s16x8 ah = *(const s16x8*)&Ah2[aoff];
            s16x8 al = *(const s16x8*)&Al2[aoff];
#pragma unroll
            for (int t = 0; t < 8; t++) {
                int boff = (t * 16 + l16) * SROW + kk + quad * 8;
                s16x8 bh = *(const s16x8*)&Bh[boff];
                s16x8 bl = *(const s16x8*)&Bl[boff];
                acc2[t] = __builtin_amdgcn_mfma_f32_16x16x32_bf16(ah, bh, acc2[t], 0, 0, 0);
                acc2[t] = __builtin_amdgcn_mfma_f32_16x16x32_bf16(ah, bl, acc2[t], 0, 0, 0);
                acc2[t] = __builtin_amdgcn_mfma_f32_16x16x32_bf16(al, bh, acc2[t], 0, 0, 0);
            }
        }
    }

#pragma unroll
    for (int r = 0; r < 4; r++) {
        int grow = row0 + wave * 16 + quad * 4 + r;
        if (grow < NODES)
#pragma unroll
            for (int t = 0; t < 8; t++)
                xw[(size_t)grow * CH + t * 16 + l16] = acc2[t][r];
    }
}

// ---- kB: interleaved z2 stream (even blocks) + GCN aggregation (odd blocks) ----
__global__ __launch_bounds__(256) void kB(const float* __restrict__ x2,
                                          const float* __restrict__ W22,
                                          const float* __restrict__ xw,
                                          const int* __restrict__ cursor,
                                          const int2* __restrict__ ell,
                                          const float* __restrict__ bg,
                                          float* __restrict__ z2v,
                                          float* __restrict__ z1) {
    int b = blockIdx.x, tid = threadIdx.x;
    int lane = tid & 63, wv = tid >> 6;
    if ((b & 1) == 0) {
        // ---- z2: wave-per-row ----
        int row = (b >> 1) * 4 + wv;
        const float4* xr = (const float4*)(x2 + (size_t)row * NODES);
        const float4* w0 = (const float4*)W22;
        const float4* w1 = (const float4*)(W22 + NODES);
        float s0 = 0.f, s1 = 0.f;
        int j = lane;
#pragma unroll 4
        for (int k = 0; k < 39; k++) {  // 39*64 = 2496 of 2500 float4
            float4 v = xr[j];
            float4 a = w0[j];
            float4 c = w1[j];
            s0 += v.x * a.x + v.y * a.y + v.z * a.z + v.w * a.w;
            s1 += v.x * c.x + v.y * c.y + v.z * c.z + v.w * c.w;
            j += 64;
        }
        if (lane < 4) {
            int jt = 2496 + lane;
            float4 v = xr[jt];
            float4 a = w0[jt];
            float4 c = w1[jt];
            s0 += v.x * a.x + v.y * a.y + v.z * a.z + v.w * a.w;
            s1 += v.x * c.x + v.y * c.y + v.z * c.z + v.w * c.w;
        }
#pragma unroll
        for (int off = 1; off < 64; off <<= 1) {
            s0 += __shfl_xor(s0, off, 64);
            s1 += __shfl_xor(s1, off, 64);
        }
        if (lane == 0) {
            float n = sqrtf(s0 * s0 + s1 * s1);
            z2v[row] = 0.8f * s0 / fmaxf(n, 1e-12f);
        }
    } else {
        // ---- agg: wave-per-node, 16-lane groups x 4 neighbors per iter ----
        int node = (b >> 1) * 4 + wv;
        int g = lane >> 4, l16 = lane & 15;
        int cnt = cursor[node];
        float di = rsqrtf((float)(cnt + 1));
        float4 a0 = {0.f, 0.f, 0.f, 0.f}, a1 = {0.f, 0.f, 0.f, 0.f};
        const int2* row = ell + node * MAXDEG;
        for (int i = g; i < cnt; i += 4) {
            int2 p = row[i];
            float w = rsqrtf((float)(cursor[p.x] + 1)) * di;
            const float4* u = (const float4*)(xw + (size_t)p.x * CH + l16 * 8);
            float4 u0 = u[0], u1 = u[1];
            a0.x += w * u0.x; a0.y += w * u0.y; a0.z += w * u0.z; a0.w += w * u0.w;
            a1.x += w * u1.x; a1.y += w * u1.y; a1.z += w * u1.z; a1.w += w * u1.w;
        }
        // cross-group reduce (channels identical across groups)
#pragma unroll
        for (int off = 16; off < 64; off <<= 1) {
            a0.x += __shfl_xor(a0.x, off, 64); a0.y += __shfl_xor(a0.y, off, 64);
            a0.z += __shfl_xor(a0.z, off, 64); a0.w += __shfl_xor(a0.w, off, 64);
            a1.x += __shfl_xor(a1.x, off, 64); a1.y += __shfl_xor(a1.y, off, 64);
            a1.z += __shfl_xor(a1.z, off, 64); a1.w += __shfl_xor(a1.w, off, 64);
        }
        if (g == 0) {
            const float4* s = (const float4*)(xw + (size_t)node * CH + l16 * 8);
            const float4* bgp = (const float4*)(bg + l16 * 8);
            float4 s0 = s[0], s1 = s[1], b0 = bgp[0], b1 = bgp[1];
            float sc = di * di;
            a0.x += s0.x * sc + b0.x; a0.y += s0.y * sc + b0.y;
            a0.z += s0.z * sc + b0.z; a0.w += s0.w * sc + b0.w;
            a1.x += s1.x * sc + b1.x; a1.y += s1.y * sc + b1.y;
            a1.z += s1.z * sc + b1.z; a1.w += s1.w * sc + b1.w;
            float4* o = (float4*)(z1 + (size_t)node * CH + l16 * 8);
            o[0] = a0;
            o[1] = a1;
        }
    }
}

// ---- kC: score, wave-per-node, 16-lane groups x 4 edges per iter ----
__global__ __launch_bounds__(256) void kC(const float* __restrict__ z1,
                                          const float* __restrict__ z2v,
                                          const int* __restrict__ cursor,
                                          const int2* __restrict__ ell,
                                          float* __restrict__ out) {
    int node = blockIdx.x * 4 + (threadIdx.x >> 6);
    int lane = threadIdx.x & 63;
    int g = lane >> 4, l16 = lane & 15;
    int cnt = cursor[node];
    float zc = z2v[node];
    const float4* vp = (const float4*)(z1 + (size_t)node * CH + l16 * 8);
    float4 v0 = vp[0], v1 = vp[1];
    const int2* row = ell + node * MAXDEG;
    for (int i = g; i < cnt; i += 4) {
        int2 p = row[i];
        const float4* up = (const float4*)(z1 + (size_t)p.x * CH + l16 * 8);
        float4 u0 = up[0], u1 = up[1];
        float d = v0.x * u0.x + v0.y * u0.y + v0.z * u0.z + v0.w * u0.w
                + v1.x * u1.x + v1.y * u1.y + v1.z * u1.z + v1.w * u1.w;
#pragma unroll
        for (int off = 1; off < 16; off <<= 1) d += __shfl_xor(d, off, 64);
        if (l16 == 0) {
            float sf = sigmoidf(d);
            float sn = sigmoidf(zc + z2v[p.x]);
            out[p.y] = sf * sf + (1.f - sf) * sn;
        }
    }
}

extern "C" void kernel_launch(void* const* d_in, const int* in_sizes, int n_in,
                              void* d_out, int out_size, void* d_ws, size_t ws_size,
                              hipStream_t stream) {
    const float* x   = (const float*)d_in[0];
    const float* x2  = (const float*)d_in[1];
    const float* W2  = (const float*)d_in[2];
    const float* b2  = (const float*)d_in[3];
    const float* Wg  = (const float*)d_in[4];
    const float* bg  = (const float*)d_in[5];
    const float* W22 = (const float*)d_in[6];
    const int*   ei  = (const int*)d_in[7];
    float* out = (float*)d_out;

    char* ws = (char*)d_ws;
    size_t off = 0;
    auto alloc = [&](size_t bytes) -> void* {
        void* p = ws + off;
        off = (off + bytes + 255) & ~(size_t)255;
        return p;
    };
    int*   cursor = (int*)alloc(NODES * 4);
    int2*  ell    = (int2*)alloc((size_t)NODES * MAXDEG * 8);
    float* xw     = (float*)alloc((size_t)NODES * CH * 4);
    float* z1     = (float*)alloc((size_t)NODES * CH * 4);
    float* z2v    = (float*)alloc(NODES * 4);

    hipMemsetAsync(cursor, 0, NODES * sizeof(int), stream);
    kA<<<GB1 + FB, 256, 0, stream>>>(x, W2, b2, Wg, ei, cursor, ell, xw);
    kB<<<ZB + AB, 256, 0, stream>>>(x2, W22, xw, cursor, ell, bg, z2v, z1);
    kC<<<SB, 256, 0, stream>>>(z1, z2v, cursor, ell, out);
}

// Round 3
// 614.555 us; speedup vs baseline: 1.1071x; 1.0971x over previous
//
#include <hip/hip_runtime.h>
#include <math.h>

#define NODES 10000
#define NEDGE 320000
#define INDIM 512
#define CH    128
#define GB1   157   // fused-gemm row-tile blocks (64 rows each)
#define FB    313   // ELL fill blocks (mixed into kA)
#define ZB    2500  // z2 blocks (4 waves each -> 10000 rows), mixed into kA
#define AB    2500  // agg blocks (4 waves each -> 10000 nodes)
#define SB    2500  // score blocks
#define MAXDEG 96   // ELL row capacity (in-degree lambda=32; P(>96) ~ 1e-19)

typedef float f32x4 __attribute__((ext_vector_type(4)));
typedef short s16x8 __attribute__((ext_vector_type(8)));
typedef short s16x4 __attribute__((ext_vector_type(4)));

__device__ __forceinline__ short f2bf(float f) {
    unsigned u = __float_as_uint(f);
    return (short)((u + 0x7fffu + ((u >> 16) & 1u)) >> 16);
}
__device__ __forceinline__ float bf2f(short s) {
    return __uint_as_float(((unsigned)(unsigned short)s) << 16);
}
__device__ __forceinline__ float sigmoidf(float v) {
    return 1.f / (1.f + __expf(-v));
}

// LDS layout (bytes). Stage1 uses Ah/Al + Bh/Bl. Stage2 reuses [0,33792) for the
// bf16-split h tile (Ah2/Al2) -- legal because all stage-1 MFMAs are barrier-drained
// before the overwrite -- and restages Bh/Bl in place from Wg.
#define SROW   72    // stage-1 LDS row pitch (shorts): 64 k + 8 pad
#define SROW2  132   // stage-2 A row pitch (shorts): 128 k + 4 pad (odd dword stride)
#define AH_OFF  0        // 64*72*2  = 9216
#define AL_OFF  9216     // 9216
#define BH_OFF  33792    // 128*72*2 = 18432
#define BL_OFF  52224    // 18432  (end 70656)
#define AH2_OFF 0        // 64*132*2 = 16896
#define AL2_OFF 16896    // 16896  (end 33792 == BH_OFF)
#define SMEM_SZ 70656

// ---- kA: three block classes, all overlapped in one launch:
//   b <  GB1           : fused GEMM  h = l2n(x@W2^T+b2)*1.8 ; xw = h@Wg^T  (MFMA-bound)
//   GB1 <= b < GB1+FB  : ELL fill from edge_index               (atomic/latency-bound)
//   b >= GB1+FB        : z2 = l2n(x2@W22^T)*0.8 col0 stream     (HBM-bound, 400 MB)
// The z2 stream is independent of everything else produced here, so it hides the
// GEMM and fill entirely. cursor is pre-zeroed by hipMemsetAsync.
__global__ __launch_bounds__(256) void kA(const float* __restrict__ x,
                                          const float* __restrict__ W2,
                                          const float* __restrict__ b2,
                                          const float* __restrict__ Wg,
                                          const int* __restrict__ ei,
                                          const float* __restrict__ x2,
                                          const float* __restrict__ W22,
                                          int* cursor, int2* __restrict__ ell,
                                          float* __restrict__ xw,
                                          float* __restrict__ z2v) {
    __shared__ __align__(16) char smem[SMEM_SZ];
    int b = blockIdx.x;
    int tid = threadIdx.x;
    int lane = tid & 63, wave = tid >> 6;

    if (b >= GB1 + FB) {
        // ---- z2: wave-per-row stream of x2 ----
        int row = (b - GB1 - FB) * 4 + wave;
        const float4* xr = (const float4*)(x2 + (size_t)row * NODES);
        const float4* w0 = (const float4*)W22;
        const float4* w1 = (const float4*)(W22 + NODES);
        float s0 = 0.f, s1 = 0.f;
        int j = lane;
#pragma unroll 4
        for (int k = 0; k < 39; k++) {  // 39*64 = 2496 of 2500 float4
            float4 v = xr[j];
            float4 a = w0[j];
            float4 c = w1[j];
            s0 += v.x * a.x + v.y * a.y + v.z * a.z + v.w * a.w;
            s1 += v.x * c.x + v.y * c.y + v.z * c.z + v.w * c.w;
            j += 64;
        }
        if (lane < 4) {
            int jt = 2496 + lane;
            float4 v = xr[jt];
            float4 a = w0[jt];
            float4 c = w1[jt];
            s0 += v.x * a.x + v.y * a.y + v.z * a.z + v.w * a.w;
            s1 += v.x * c.x + v.y * c.y + v.z * c.z + v.w * c.w;
        }
#pragma unroll
        for (int off = 1; off < 64; off <<= 1) {
            s0 += __shfl_xor(s0, off, 64);
            s1 += __shfl_xor(s1, off, 64);
        }
        if (lane == 0) {
            float n = sqrtf(s0 * s0 + s1 * s1);
            z2v[row] = 0.8f * s0 / fmaxf(n, 1e-12f);
        }
        return;
    }
    if (b >= GB1) {
        // ---- ELL fill: independent of the GEMMs, overlaps with them here ----
        for (int e = (b - GB1) * 256 + tid; e < NEDGE; e += FB * 256) {
            int c = ei[NEDGE + e], src = ei[e];
            int pos = atomicAdd(&cursor[c], 1);
            if (pos < MAXDEG) ell[c * MAXDEG + pos] = make_int2(src, e);
        }
        return;
    }
    short* Ah  = (short*)(smem + AH_OFF);
    short* Al  = (short*)(smem + AL_OFF);
    short* Bh  = (short*)(smem + BH_OFF);
    short* Bl  = (short*)(smem + BL_OFF);
    short* Ah2 = (short*)(smem + AH2_OFF);
    short* Al2 = (short*)(smem + AL2_OFF);

    int quad = lane >> 4, l16 = lane & 15;
    int row0 = b * 64;

    // ================= stage 1: acc = x_tile @ W2^T =================
    f32x4 acc[8];
#pragma unroll
    for (int t = 0; t < 8; t++) acc[t] = (f32x4){0.f, 0.f, 0.f, 0.f};

    for (int kb = 0; kb < INDIM; kb += 64) {
        __syncthreads();
#pragma unroll
        for (int i = 0; i < 4; i++) {  // A tile: 64 rows x 64 k (split bf16 hi/lo)
            int idx = tid + 256 * i;
            int j = idx & 15, r = idx >> 4;
            float4 v = {0.f, 0.f, 0.f, 0.f};
            int grow = row0 + r;
            if (grow < NODES) v = *(const float4*)(x + (size_t)grow * INDIM + kb + 4 * j);
            float vv[4] = {v.x, v.y, v.z, v.w};
            s16x4 h4, l4;
#pragma unroll
            for (int q = 0; q < 4; q++) {
                short hs = f2bf(vv[q]);
                h4[q] = hs;
                l4[q] = f2bf(vv[q] - bf2f(hs));
            }
            *(s16x4*)&Ah[r * SROW + 4 * j] = h4;
            *(s16x4*)&Al[r * SROW + 4 * j] = l4;
        }
#pragma unroll
        for (int i = 0; i < 8; i++) {  // B tile: 128 n x 64 k from W2
            int idx = tid + 256 * i;
            int j = idx & 15, n = idx >> 4;
            float4 v = *(const float4*)(W2 + (size_t)n * INDIM + kb + 4 * j);
            float vv[4] = {v.x, v.y, v.z, v.w};
            s16x4 h4, l4;
#pragma unroll
            for (int q = 0; q < 4; q++) {
                short hs = f2bf(vv[q]);
                h4[q] = hs;
                l4[q] = f2bf(vv[q] - bf2f(hs));
            }
            *(s16x4*)&Bh[n * SROW + 4 * j] = h4;
            *(s16x4*)&Bl[n * SROW + 4 * j] = l4;
        }
        __syncthreads();

#pragma unroll
        for (int kk = 0; kk < 64; kk += 32) {
            int aoff = (wave * 16 + l16) * SROW + kk + quad * 8;
            s16x8 ah = *(const s16x8*)&Ah[aoff];
            s16x8 al = *(const s16x8*)&Al[aoff];
#pragma unroll
            for (int t = 0; t < 8; t++) {
                int boff = (t * 16 + l16) * SROW + kk + quad * 8;
                s16x8 bh = *(const s16x8*)&Bh[boff];
                s16x8 bl = *(const s16x8*)&Bl[boff];
                acc[t] = __builtin_amdgcn_mfma_f32_16x16x32_bf16(ah, bh, acc[t], 0, 0, 0);
                acc[t] = __builtin_amdgcn_mfma_f32_16x16x32_bf16(ah, bl, acc[t], 0, 0, 0);
                acc[t] = __builtin_amdgcn_mfma_f32_16x16x32_bf16(al, bh, acc[t], 0, 0, 0);
            }
        }
    }

    // bias + row l2-normalize * 1.8  (row cols live across the 16 lanes of each quad)
#pragma unroll
    for (int t = 0; t < 8; t++) {
        float bv = b2[t * 16 + l16];
#pragma unroll
        for (int r = 0; r < 4; r++) acc[t][r] += bv;
    }
#pragma unroll
    for (int r = 0; r < 4; r++) {
        float ss = 0.f;
#pragma unroll
        for (int t = 0; t < 8; t++) ss += acc[t][r] * acc[t][r];
#pragma unroll
        for (int off = 1; off < 16; off <<= 1) ss += __shfl_xor(ss, off, 64);
        float scale = 1.8f / fmaxf(sqrtf(ss), 1e-12f);
#pragma unroll
        for (int t = 0; t < 8; t++) acc[t][r] *= scale;
    }

    // ================= h tile -> LDS (bf16 hi/lo), becomes stage-2 A =================
    __syncthreads();  // drain all stage-1 LDS reads before overwriting [0,33792)
#pragma unroll
    for (int t = 0; t < 8; t++) {
#pragma unroll
        for (int r = 0; r < 4; r++) {
            int row = wave * 16 + quad * 4 + r;
            int col = t * 16 + l16;
            float v = acc[t][r];
            short hs = f2bf(v);
            Ah2[row * SROW2 + col] = hs;
            Al2[row * SROW2 + col] = f2bf(v - bf2f(hs));
        }
    }

    // ================= stage 2: acc2 = h_tile @ Wg^T (K=128) =================
    f32x4 acc2[8];
#pragma unroll
    for (int t = 0; t < 8; t++) acc2[t] = (f32x4){0.f, 0.f, 0.f, 0.f};

    for (int kb = 0; kb < CH; kb += 64) {
        __syncthreads();  // also orders Ah2/Al2 writes before first MFMA read
#pragma unroll
        for (int i = 0; i < 8; i++) {  // B tile: 128 n x 64 k from Wg
            int idx = tid + 256 * i;
            int j = idx & 15, n = idx >> 4;
            float4 v = *(const float4*)(Wg + (size_t)n * CH + kb + 4 * j);
            float vv[4] = {v.x, v.y, v.z, v.w};
            s16x4 h4, l4;
#pragma unroll
            for (int q = 0; q < 4; q++) {
                short hs = f2bf(vv[q]);
                h4[q] = hs;
                l4[q] = f2bf(vv[q] - bf2f(hs));
            }
            *(s16x4*)&Bh[n * SROW + 4 * j] = h4;
            *(s16x4*)&Bl[n * SROW + 4 * j] = l4;
        }
        __syncthreads();

#pragma unroll
        for (int kk = 0; kk < 64; kk += 32) {
            int aoff = (wave * 16 + l16) * SROW2 + kb + kk + quad * 8;
            s16x8 ah = *(const s16x8*)&Ah2[aoff];
            s16x8 al = *(const s16x8*)&Al2[aoff];
#pragma unroll
            for (int t = 0; t < 8; t++) {
                int boff = (t * 16 + l16) * SROW + kk + quad * 8;
                s16x8 bh = *(const s16x8*)&Bh[boff];
                s16x8 bl = *(const s16x8*)&Bl[boff];
                acc2[t] = __builtin_amdgcn_mfma_f32_16x16x32_bf16(ah, bh, acc2[t], 0, 0, 0);
                acc2[t] = __builtin_amdgcn_mfma_f32_16x16x32_bf16(ah, bl, acc2[t], 0, 0, 0);
                acc2[t] = __builtin_amdgcn_mfma_f32_16x16x32_bf16(al, bh, acc2[t], 0, 0, 0);
            }
        }
    }

#pragma unroll
    for (int r = 0; r < 4; r++) {
        int grow = row0 + wave * 16 + quad * 4 + r;
        if (grow < NODES)
#pragma unroll
            for (int t = 0; t < 8; t++)
                xw[(size_t)grow * CH + t * 16 + l16] = acc2[t][r];
    }
}

// ---- kB: GCN aggregation only (z2 moved into kA). Wave-per-node. ----
__global__ __launch_bounds__(256) void kB(const float* __restrict__ xw,
                                          const int* __restrict__ cursor,
                                          const int2* __restrict__ ell,
                                          const float* __restrict__ bg,
                                          float* __restrict__ z1) {
    int node = blockIdx.x * 4 + (threadIdx.x >> 6);
    int lane = threadIdx.x & 63;
    int g = lane >> 4, l16 = lane & 15;
    int cnt = cursor[node];
    float di = rsqrtf((float)(cnt + 1));
    float4 a0 = {0.f, 0.f, 0.f, 0.f}, a1 = {0.f, 0.f, 0.f, 0.f};
    const int2* row = ell + node * MAXDEG;
    for (int i = g; i < cnt; i += 4) {
        int2 p = row[i];
        float w = rsqrtf((float)(cursor[p.x] + 1)) * di;
        const float4* u = (const float4*)(xw + (size_t)p.x * CH + l16 * 8);
        float4 u0 = u[0], u1 = u[1];
        a0.x += w * u0.x; a0.y += w * u0.y; a0.z += w * u0.z; a0.w += w * u0.w;
        a1.x += w * u1.x; a1.y += w * u1.y; a1.z += w * u1.z; a1.w += w * u1.w;
    }
    // cross-group reduce (channels identical across groups)
#pragma unroll
    for (int off = 16; off < 64; off <<= 1) {
        a0.x += __shfl_xor(a0.x, off, 64); a0.y += __shfl_xor(a0.y, off, 64);
        a0.z += __shfl_xor(a0.z, off, 64); a0.w += __shfl_xor(a0.w, off, 64);
        a1.x += __shfl_xor(a1.x, off, 64); a1.y += __shfl_xor(a1.y, off, 64);
        a1.z += __shfl_xor(a1.z, off, 64); a1.w += __shfl_xor(a1.w, off, 64);
    }
    if (g == 0) {
        const float4* s = (const float4*)(xw + (size_t)node * CH + l16 * 8);
        const float4* bgp = (const float4*)(bg + l16 * 8);
        float4 s0 = s[0], s1 = s[1], b0 = bgp[0], b1 = bgp[1];
        float sc = di * di;
        a0.x += s0.x * sc + b0.x; a0.y += s0.y * sc + b0.y;
        a0.z += s0.z * sc + b0.z; a0.w += s0.w * sc + b0.w;
        a1.x += s1.x * sc + b1.x; a1.y += s1.y * sc + b1.y;
        a1.z += s1.z * sc + b1.z; a1.w += s1.w * sc + b1.w;
        float4* o = (float4*)(z1 + (size_t)node * CH + l16 * 8);
        o[0] = a0;
        o[1] = a1;
    }
}

// ---- kC: score, wave-per-node, 16-lane groups x 4 edges per iter ----
__global__ __launch_bounds__(256) void kC(const float* __restrict__ z1,
                                          const float* __restrict__ z2v,
                                          const int* __restrict__ cursor,
                                          const int2* __restrict__ ell,
                                          float* __restrict__ out) {
    int node = blockIdx.x * 4 + (threadIdx.x >> 6);
    int lane = threadIdx.x & 63;
    int g = lane >> 4, l16 = lane & 15;
    int cnt = cursor[node];
    float zc = z2v[node];
    const float4* vp = (const float4*)(z1 + (size_t)node * CH + l16 * 8);
    float4 v0 = vp[0], v1 = vp[1];
    const int2* row = ell + node * MAXDEG;
    for (int i = g; i < cnt; i += 4) {
        int2 p = row[i];
        const float4* up = (const float4*)(z1 + (size_t)p.x * CH + l16 * 8);
        float4 u0 = up[0], u1 = up[1];
        float d = v0.x * u0.x + v0.y * u0.y + v0.z * u0.z + v0.w * u0.w
                + v1.x * u1.x + v1.y * u1.y + v1.z * u1.z + v1.w * u1.w;
#pragma unroll
        for (int off = 1; off < 16; off <<= 1) d += __shfl_xor(d, off, 64);
        if (l16 == 0) {
            float sf = sigmoidf(d);
            float sn = sigmoidf(zc + z2v[p.x]);
            out[p.y] = sf * sf + (1.f - sf) * sn;
        }
    }
}

extern "C" void kernel_launch(void* const* d_in, const int* in_sizes, int n_in,
                              void* d_out, int out_size, void* d_ws, size_t ws_size,
                              hipStream_t stream) {
    const float* x   = (const float*)d_in[0];
    const float* x2  = (const float*)d_in[1];
    const float* W2  = (const float*)d_in[2];
    const float* b2  = (const float*)d_in[3];
    const float* Wg  = (const float*)d_in[4];
    const float* bg  = (const float*)d_in[5];
    const float* W22 = (const float*)d_in[6];
    const int*   ei  = (const int*)d_in[7];
    float* out = (float*)d_out;

    char* ws = (char*)d_ws;
    size_t off = 0;
    auto alloc = [&](size_t bytes) -> void* {
        void* p = ws + off;
        off = (off + bytes + 255) & ~(size_t)255;
        return p;
    };
    int*   cursor = (int*)alloc(NODES * 4);
    int2*  ell    = (int2*)alloc((size_t)NODES * MAXDEG * 8);
    float* xw     = (float*)alloc((size_t)NODES * CH * 4);
    float* z1     = (float*)alloc((size_t)NODES * CH * 4);
    float* z2v    = (float*)alloc(NODES * 4);

    hipMemsetAsync(cursor, 0, NODES * sizeof(int), stream);
    kA<<<GB1 + FB + ZB, 256, 0, stream>>>(x, W2, b2, Wg, ei, x2, W22,
                                          cursor, ell, xw, z2v);
    kB<<<AB, 256, 0, stream>>>(xw, cursor, ell, bg, z1);
    kC<<<SB, 256, 0, stream>>>(z1, z2v, cursor, ell, out);
}